// Round 9
// baseline (238.891 us; speedup 1.0000x reference)
//
#include <hip/hip_runtime.h>
#include <hip/hip_bf16.h>

#define HID 128
#define LDK 136    // LDS row stride in shorts (272B): +4-bank skew/row, additive offsets
#define CPB 4      // cells per edge-block
#define CAP 16     // edges per cell (E/G)

// wt regions (bf16 elements): Wt[n][k] transposed weights
#define WT_M1L 0       // [128][128] mw1 rows 0..127   (prep_gemm)
#define WT_M2  16384   // [128][128]
#define WT_U1  32768   // [128][128]
#define WT_U2  49152   // [128][128]
#define WT_T   65536   // [128][128] Tt[n][a] = sum_f ew2[a][f]*mw1[128+f][n]
#define WT_TOTAL 81920

typedef __attribute__((ext_vector_type(8))) short bf16x8;
typedef __attribute__((ext_vector_type(4))) float f32x4;

#define MFMA(a, b, c) __builtin_amdgcn_mfma_f32_16x16x32_bf16(a, b, c, 0, 0, 0)

__device__ __forceinline__ float silu_f(float x) {
    return x * (1.0f / (1.0f + __expf(-x)));
}

__device__ __forceinline__ short f2b(float x) {
    __hip_bfloat16 h = __float2bfloat16(x);   // RNE
    return *(short*)&h;
}

// fp16 <-> fp32 via _Float16 (v_cvt_f32_f16 / v_cvt_f16_f32)
__device__ __forceinline__ float h2f(unsigned short u) {
    union { unsigned short s; _Float16 h; } v; v.s = u; return (float)v.h;
}
__device__ __forceinline__ unsigned short f2h(float x) {
    union { unsigned short s; _Float16 h; } v; v.h = (_Float16)x; return v.s;
}

// Fully-unrolled K=128 GEMM over 4 A-row-tiles x 32 weight cols.
template<int LDB, bool SWAP>
__device__ __forceinline__ void gemm128(f32x4 acc[4][2], const short* actb,
                                        const short* __restrict__ w0)
{
    const short* __restrict__ w1 = w0 + 16 * LDB;
    #pragma unroll
    for (int ks = 0; ks < 4; ++ks) {
        bf16x8 wa = *(const bf16x8*)(w0 + ks * 32);
        bf16x8 wb = *(const bf16x8*)(w1 + ks * 32);
        #pragma unroll
        for (int e4 = 0; e4 < 4; ++e4) {
            bf16x8 a = *(const bf16x8*)(actb + e4 * (16 * LDK) + ks * 32);
            if (SWAP) {
                acc[e4][0] = MFMA(wa, a, acc[e4][0]);
                acc[e4][1] = MFMA(wb, a, acc[e4][1]);
            } else {      // act as A: C rows = act rows, cols = weight cols
                acc[e4][0] = MFMA(a, wa, acc[e4][0]);
                acc[e4][1] = MFMA(a, wb, acc[e4][1]);
            }
        }
    }
}

// Small 16-row K=128 GEMM: A = 16 LDS rows, B = 32 weight cols.
__device__ __forceinline__ void gemm16(f32x4 a2[2], const short* ab,
                                       const short* __restrict__ w0)
{
    const short* __restrict__ w1 = w0 + 16 * 128;
    #pragma unroll
    for (int ks = 0; ks < 4; ++ks) {
        bf16x8 a  = *(const bf16x8*)(ab + ks * 32);
        bf16x8 b0 = *(const bf16x8*)(w0 + ks * 32);
        bf16x8 b1 = *(const bf16x8*)(w1 + ks * 32);
        a2[0] = MFMA(a, b0, a2[0]);
        a2[1] = MFMA(a, b1, a2[1]);
    }
}

// ---------------------------------------------------------------------------
// prep0: binning | wt transpose-cvt | T fold | bias2 | preN | preC
// ---------------------------------------------------------------------------
extern "C" __global__ void __launch_bounds__(256)
prep0(const int* __restrict__ ei, int* __restrict__ cnt, int* __restrict__ bin, int E,
      const float* __restrict__ ew1, const float* __restrict__ eb1,
      const float* __restrict__ ew2, const float* __restrict__ eb2,
      const float* __restrict__ mw1, const float* __restrict__ mw2,
      const float* __restrict__ uw1, const float* __restrict__ uw2,
      const float* __restrict__ npos, const float* __restrict__ gpos,
      short* __restrict__ wt, float* __restrict__ bias2,
      unsigned short* __restrict__ preX, unsigned short* __restrict__ preC,
      int NN, int G)
{
    int nbin = (E + 255) / 256;
    int b = blockIdx.x;
    int t = threadIdx.x;
    if (b < nbin) {                      // binning: store SOURCE NODE id
        int e = b * 256 + t;
        if (e < E) {
            int j = ei[E + e];
            int i = ei[e];
            int slot = atomicAdd(&cnt[j], 1);
            if (slot < CAP) bin[(size_t)j * CAP + slot] = i;
        }
        return;
    }
    b -= nbin;
    if (b < 256) {                       // transpose-convert M1L/M2/U1/U2
        int idx = b * 256 + t;
        int reg = idx >> 14, r = idx & 16383;
        int n = r >> 7, k = r & 127;
        const float* src = (reg == 0) ? mw1 : (reg == 1) ? mw2 : (reg == 2) ? uw1 : uw2;
        wt[idx] = f2b(src[k * HID + n]);
        return;
    }
    b -= 256;
    if (b < 64) {                        // Tt[n][a] = sum_f ew2[a][f]*mw1[128+f][n]
        int idx = b * 256 + t;
        int n = idx >> 7, a = idx & 127;
        const float* er = ew2 + (size_t)a * HID;
        float s = 0.0f;
        for (int f = 0; f < HID; ++f)
            s = fmaf(er[f], mw1[(size_t)(HID + f) * HID + n], s);
        wt[WT_T + idx] = f2b(s);
        return;
    }
    b -= 64;
    if (b < 1) {                         // bias2[n] = sum_f eb2[f]*mw1[128+f][n]
        if (t < HID) {
            float s = 0.0f;
            for (int f = 0; f < HID; ++f)
                s = fmaf(eb2[f], mw1[(size_t)(HID + f) * HID + t], s);
            bias2[t] = s;
        }
        return;
    }
    b -= 1;
    int nN = (NN * HID) / 2048;          // preN blocks (8 outputs/thread)
    if (b < nN) {                        // preX[node][0:128] = np . ew1[0:3]  (fp16)
        int idx = b * 256 + t;
        int node = idx >> 4, f0 = (idx & 15) * 8;
        const float* np = npos + (size_t)node * 3;
        float n0 = np[0], n1 = np[1], n2 = np[2];
        const float* w0 = ew1 + 0 * HID + f0;
        const float* w1 = ew1 + 1 * HID + f0;
        const float* w2 = ew1 + 2 * HID + f0;
        union { unsigned short us[8]; uint4 q; } o;
        #pragma unroll
        for (int j = 0; j < 8; ++j)
            o.us[j] = f2h(n0 * w0[j] + n1 * w1[j] + n2 * w2[j]);
        *(uint4*)(preX + (size_t)node * 256 + f0) = o.q;
        return;
    }
    b -= nN;
    {                                    // preC[cell] = gp . ew1[3:6] + eb1  (fp16)
        int idx = b * 256 + t;
        if (idx < G * (HID / 8)) {
            int cell = idx >> 4, f0 = (idx & 15) * 8;
            const float* gp = gpos + (size_t)cell * 3;
            float g0 = gp[0], g1 = gp[1], g2 = gp[2];
            const float* w3 = ew1 + 3 * HID + f0;
            const float* w4 = ew1 + 4 * HID + f0;
            const float* w5 = ew1 + 5 * HID + f0;
            const float* bb = eb1 + f0;
            union { unsigned short us[8]; uint4 q; } o;
            #pragma unroll
            for (int j = 0; j < 8; ++j)
                o.us[j] = f2h(g0 * w3[j] + g1 * w4[j] + g2 * w5[j] + bb[j]);
            *(uint4*)(preC + (size_t)cell * HID + f0) = o.q;
        }
    }
}

// ---------------------------------------------------------------------------
// prep_gemm: preX[node][128:256] = emb[node] @ mw1[:128] + mb1 + bias2 (fp16)
// ---------------------------------------------------------------------------
extern "C" __global__ void __launch_bounds__(256, 4)
prep_gemm(const float* __restrict__ emb, const float* __restrict__ mb1,
          const float* __restrict__ bias2, const short* __restrict__ wt,
          unsigned short* __restrict__ preX)
{
    __shared__ short s_x[64 * LDK];
    const int t  = threadIdx.x;
    const int r0 = blockIdx.x * 64;

    {   // stage 64 fp32 rows -> bf16 LDS (padded rows)
        int row = t >> 2, part = t & 3;
        const float4* src = (const float4*)(emb + (size_t)(r0 + row) * HID + part * 32);
        short* dst = s_x + row * LDK + part * 32;
        #pragma unroll
        for (int c = 0; c < 4; ++c) {
            float4 v0 = src[c * 2], v1 = src[c * 2 + 1];
            short4 a4, b4;
            a4.x = f2b(v0.x); a4.y = f2b(v0.y); a4.z = f2b(v0.z); a4.w = f2b(v0.w);
            b4.x = f2b(v1.x); b4.y = f2b(v1.y); b4.z = f2b(v1.z); b4.w = f2b(v1.w);
            *(short4*)(dst + c * 8)     = a4;
            *(short4*)(dst + c * 8 + 4) = b4;
        }
    }
    __syncthreads();

    const int lane = t & 63, q = lane & 15, h = lane >> 4, nb = (t >> 6) * 32;
    f32x4 acc[4][2];
    #pragma unroll
    for (int m = 0; m < 4; ++m) { acc[m][0] = (f32x4)(0.0f); acc[m][1] = (f32x4)(0.0f); }
    gemm128<128, false>(acc, s_x + q * LDK + h * 8, wt + WT_M1L + (nb + q) * 128 + h * 8);

    #pragma unroll
    for (int nf = 0; nf < 2; ++nf) {
        int n = nb + nf * 16 + q;
        float bb = mb1[n] + bias2[n];
        #pragma unroll
        for (int m = 0; m < 4; ++m)
            #pragma unroll
            for (int r = 0; r < 4; ++r)
                preX[(size_t)(r0 + m * 16 + h * 4 + r) * 256 + 128 + n] =
                    f2h(acc[m][nf][r] + bb);
    }
}

// ---------------------------------------------------------------------------
// edge kernel: h1 = silu(preN gather + preC gather) -> T-GEMM -> silu+pre in
// regs -> per-cell sum -> 3 tiny GEMMs -> out. No npos/gpos/ew1 access.
// ---------------------------------------------------------------------------
extern "C" __global__ void __launch_bounds__(256, 5)
edge_kernel(const float* __restrict__ mb2,
            const float* __restrict__ ub1, const float* __restrict__ ub2,
            const short* __restrict__ wt,
            const int* __restrict__ cnt,
            const int* __restrict__ bin,
            const unsigned short* __restrict__ preX,
            const unsigned short* __restrict__ preC,
            float* __restrict__ out)
{
    __shared__ short s_h1[64 * LDK];   // h1 acts
    __shared__ short s_m1[16 * LDK];   // cell sums (rows 0..3 real)
    __shared__ short s_m2[16 * LDK];   // mean@mw2+mb2
    __shared__ short s_u [16 * LDK];   // u1
    __shared__ int   s_bin[64];

    const int t  = threadIdx.x;
    const int c0 = blockIdx.x * CPB;
    const int lane = t & 63, q = lane & 15, h = lane >> 4, nb = (t >> 6) * 32;
    const int ew = t & 63;             // edge within block (wave-invariant)
    const int fc = t >> 6;             // feat chunk = wave id

    int id_e = bin[c0 * CAP + ew];
    if (t < 64) s_bin[t] = id_e;

    float inv[4];
    #pragma unroll
    for (int m = 0; m < 4; ++m) {
        int c = cnt[c0 + m];
        inv[m] = 1.0f / (float)(c > 0 ? c : 1);
    }

    // ---- h1: feats fc*32..+31 of edge ew = silu(preN + preC) -> s_h1
    {
        const unsigned short* pn = preX + (size_t)id_e * 256 + fc * 32;
        const unsigned short* pc = preC + (size_t)(c0 + (ew >> 4)) * HID + fc * 32;
        union { uint4 q4[4]; unsigned short us[32]; } A, C;
        #pragma unroll
        for (int ci = 0; ci < 4; ++ci) {
            A.q4[ci] = *(const uint4*)(pn + ci * 8);
            C.q4[ci] = *(const uint4*)(pc + ci * 8);
        }
        short* dst = s_h1 + ew * LDK + fc * 32;
        #pragma unroll
        for (int ci = 0; ci < 4; ++ci) {
            union { short s[8]; uint4 q; } O;
            #pragma unroll
            for (int j = 0; j < 8; ++j)
                O.s[j] = f2b(silu_f(h2f(A.us[ci * 8 + j]) + h2f(C.us[ci * 8 + j])));
            *(uint4*)(dst + ci * 8) = O.q;
        }
    }
    __syncthreads();                                   // B1: h1 + s_bin visible

    // ---- pre-gather (h2 bias) for T-epi rows (m*16+h*4+r), cols nb(+16)+q
    unsigned short pA[4][4], pB[4][4];
    #pragma unroll
    for (int m = 0; m < 4; ++m) {
        #pragma unroll
        for (int r = 0; r < 4; ++r) {
            int id = s_bin[m * 16 + h * 4 + r];
            const unsigned short* pr = preX + (size_t)id * 256 + 128;
            pA[m][r] = pr[nb + q];
            pB[m][r] = pr[nb + 16 + q];
        }
    }

    // ---- T-GEMM: h2in = h1 @ T  (actA: C rows = edges, cols nb(+16)+q)
    f32x4 acc[4][2];
    #pragma unroll
    for (int m = 0; m < 4; ++m) { acc[m][0] = (f32x4)(0.0f); acc[m][1] = (f32x4)(0.0f); }
    gemm128<128, false>(acc, s_h1 + q * LDK + h * 8, wt + WT_T + (nb + q) * 128 + h * 8);

    // ---- silu(h2in + pre) in regs; per-cell sum (r-sum + h-shfl) -> s_m1
    #pragma unroll
    for (int m = 0; m < 4; ++m) {
        #pragma unroll
        for (int nf = 0; nf < 2; ++nf) {
            f32x4 v = acc[m][nf];
            float s = silu_f(v[0] + h2f(nf ? pB[m][0] : pA[m][0]));
            s += silu_f(v[1] + h2f(nf ? pB[m][1] : pA[m][1]));
            s += silu_f(v[2] + h2f(nf ? pB[m][2] : pA[m][2]));
            s += silu_f(v[3] + h2f(nf ? pB[m][3] : pA[m][3]));
            s += __shfl_xor(s, 16);
            s += __shfl_xor(s, 32);
            if (h == 0)
                s_m1[m * LDK + nb + nf * 16 + q] = f2b(s);   // SUM (1/c deferred)
        }
    }
    __syncthreads();                                   // B2: sums visible

    // ---- G1: mean = (S @ mw2)*inv + mb2 -> s_m2 (rows 0..3; exact fp32 inv)
    f32x4 a2[2];
    a2[0] = (f32x4)(0.0f); a2[1] = (f32x4)(0.0f);
    gemm16(a2, s_m1 + q * LDK + h * 8, wt + WT_M2 + (nb + q) * 128 + h * 8);
    if (h == 0) {
        #pragma unroll
        for (int nf = 0; nf < 2; ++nf) {
            int n = nb + nf * 16 + q;
            float bb = mb2[n];
            #pragma unroll
            for (int r = 0; r < 4; ++r)
                s_m2[r * LDK + n] = f2b(a2[nf][r] * inv[r] + bb);
        }
    }
    __syncthreads();                                   // B3

    // ---- G2: u1 = silu(mean @ uw1 + ub1) -> s_u (rows 0..3)
    a2[0] = (f32x4)(0.0f); a2[1] = (f32x4)(0.0f);
    gemm16(a2, s_m2 + q * LDK + h * 8, wt + WT_U1 + (nb + q) * 128 + h * 8);
    if (h == 0) {
        #pragma unroll
        for (int nf = 0; nf < 2; ++nf) {
            int n = nb + nf * 16 + q;
            float bb = ub1[n];
            #pragma unroll
            for (int r = 0; r < 4; ++r)
                s_u[r * LDK + n] = f2b(silu_f(a2[nf][r] + bb));
        }
    }
    __syncthreads();                                   // B4

    // ---- G3: out = u1 @ uw2 + ub2  (C rows 0..3 = cells)
    a2[0] = (f32x4)(0.0f); a2[1] = (f32x4)(0.0f);
    gemm16(a2, s_u + q * LDK + h * 8, wt + WT_U2 + (nb + q) * 128 + h * 8);
    if (h == 0) {
        #pragma unroll
        for (int nf = 0; nf < 2; ++nf) {
            int n = nb + nf * 16 + q;
            float bb = ub2[n];
            #pragma unroll
            for (int r = 0; r < 4; ++r)
                out[(size_t)(c0 + r) * HID + n] = a2[nf][r] + bb;
        }
    }
}

// ---------------------------------------------------------------------------
extern "C" void kernel_launch(void* const* d_in, const int* in_sizes, int n_in,
                              void* d_out, int out_size, void* d_ws, size_t ws_size,
                              hipStream_t stream)
{
    const float* emb  = (const float*)d_in[0];
    const float* npos = (const float*)d_in[1];
    const float* gpos = (const float*)d_in[2];
    const int*   ei   = (const int*)d_in[3];
    const float* ew1  = (const float*)d_in[4];
    const float* eb1  = (const float*)d_in[5];
    const float* ew2  = (const float*)d_in[6];
    const float* eb2  = (const float*)d_in[7];
    const float* mw1  = (const float*)d_in[8];
    const float* mb1  = (const float*)d_in[9];
    const float* mw2  = (const float*)d_in[10];
    const float* mb2  = (const float*)d_in[11];
    const float* uw1  = (const float*)d_in[12];
    const float* ub1  = (const float*)d_in[13];
    const float* uw2  = (const float*)d_in[14];
    const float* ub2  = (const float*)d_in[15];

    const int E  = in_sizes[3] / 2;
    const int G  = in_sizes[2] / 3;
    const int NN = in_sizes[0] / HID;

    // ws: preX fp16[NN*256] | preC fp16[G*128] | cnt int[G] | bin int[G*CAP]
    //   | wt bf16[WT_TOTAL] | bias2 f32[128]      (~44.3 MB total)
    unsigned short* preX = (unsigned short*)d_ws;
    unsigned short* preC = preX + (size_t)NN * 256;
    char* p = (char*)(preC + (size_t)G * HID);
    int*   cnt = (int*)p;                 p += (size_t)G * 4;
    int*   bin = (int*)p;                 p += (size_t)G * CAP * 4;
    short* wt  = (short*)p;               p += (size_t)WT_TOTAL * 2;
    float* bias2 = (float*)p;

    hipMemsetAsync(cnt, 0, (size_t)G * (4 + CAP * 4), stream);   // cnt + bin

    int nbin = (E + 255) / 256;
    int nN   = (NN * HID) / 2048;
    int nC   = (G * HID) / 2048;
    prep0<<<nbin + 256 + 64 + 1 + nN + nC, 256, 0, stream>>>(
        ei, cnt, bin, E, ew1, eb1, ew2, eb2, mw1, mw2, uw1, uw2,
        npos, gpos, wt, bias2, preX, preC, NN, G);
    prep_gemm<<<NN / 64, 256, 0, stream>>>(emb, mb1, bias2, wt, preX);
    edge_kernel<<<G / CPB, 256, 0, stream>>>(mb2, ub1, ub2, wt, cnt, bin,
                                             preX, preC, (float*)d_out);
}